// Round 17
// baseline (227.923 us; speedup 1.0000x reference)
//
#include <hip/hip_runtime.h>
#include <stdint.h>

#define N_NODES 50000
#define DIN     512
#define DOUT    128
#define NSUP    2
#define EDGES   800000
#define NEDGE   (NSUP * EDGES)        // 1,600,000
#define NROWS   (NSUP * N_NODES)      // 100,000
#define NB      782                   // ceil(NROWS/128)
#define CH      8192                  // edges per chunk
#define NCH     ((NEDGE + CH - 1) / CH)   // 196
#define EPT     16                    // CH / 512 threads
#define SCAP    4096                  // per-bucket LDS edge capacity (max ~2300)
#define NMASKW  ((N_NODES * DIN) / 32)    // 800,000 mask words
#define NMB     1563                  // mask blocks: 1563*512 = 800,256 threads
#define NWC     256                   // wcvt blocks: 256*512 = 131,072 elems

typedef __attribute__((ext_vector_type(8))) short short8;
typedef __attribute__((ext_vector_type(4))) float f32x4;

// ---- JAX threefry2x32, key(42) -> (0,42); partitionable, bits = o0^o1 (verified R1) ----
__device__ __forceinline__ uint32_t rotl32(uint32_t v, uint32_t d) {
  return (v << d) | (v >> (32u - d));
}

__device__ __forceinline__ void threefry2x32(uint32_t x0, uint32_t x1,
                                             uint32_t& o0, uint32_t& o1) {
  const uint32_t ks0 = 0u;
  const uint32_t ks1 = 42u;
  const uint32_t ks2 = 0u ^ 42u ^ 0x1BD11BDAu;
  x0 += ks0; x1 += ks1;
#define TF_R(r) { x0 += x1; x1 = rotl32(x1, (r)); x1 ^= x0; }
  TF_R(13) TF_R(15) TF_R(26) TF_R(6)
  x0 += ks1; x1 += ks2 + 1u;
  TF_R(17) TF_R(29) TF_R(16) TF_R(24)
  x0 += ks2; x1 += ks0 + 2u;
  TF_R(13) TF_R(15) TF_R(26) TF_R(6)
  x0 += ks0; x1 += ks1 + 3u;
  TF_R(17) TF_R(29) TF_R(16) TF_R(24)
  x0 += ks1; x1 += ks2 + 4u;
  TF_R(13) TF_R(15) TF_R(26) TF_R(6)
  x0 += ks2; x1 += ks0 + 5u;
#undef TF_R
  o0 = x0; o1 = x1;
}

__device__ __forceinline__ bool keep_mask(uint32_t idx) {
  uint32_t o0, o1;
  threefry2x32(0u, idx, o0, o1);
  return ((o0 ^ o1) >> 31) == 0u;   // u<0.5 <=> MSB(o0^o1)==0
}

__device__ __forceinline__ uint32_t pack_bf16x2(float a, float b) {
  uint32_t ua = __float_as_uint(a), ub = __float_as_uint(b);
  ua += 0x7fffu + ((ua >> 16) & 1u);
  ub += 0x7fffu + ((ub >> 16) & 1u);
  return (ua >> 16) | (ub & 0xffff0000u);
}

__device__ __forceinline__ uint32_t bf16rne(float f) {
  uint32_t u = __float_as_uint(f);
  u += 0x7fffu + ((u >> 16) & 1u);
  return u >> 16;
}

__device__ __forceinline__ short8 conv8(float4 a, float4 b, uint32_t bits) {
  float f[8] = {a.x, a.y, a.z, a.w, b.x, b.y, b.z, b.w};
  union { uint32_t u[4]; short8 s; } pk;
#pragma unroll
  for (int q = 0; q < 8; ++q)
    f[q] = ((bits >> q) & 1u) ? f[q] * 2.0f : 0.0f;
#pragma unroll
  for (int q = 0; q < 4; ++q) pk.u[q] = pack_bf16x2(f[2 * q], f[2 * q + 1]);
  return pk.s;
}

// ---- heterogeneous fused pre-pass ----
// blocks [0, NCH):          edge bucket histogram (memory-bound)
// blocks [NCH, NCH+NMB):    dropout mask, 1 word/thread, unroll-8 ILP (VALU)
// blocks [NCH+NMB, +NWC):   W fp32 -> b16r in MFMA-FRAGMENT order:
//   b16r[((kc8*16+nf)*2+kk)*512 + lane*8 + j] = bf16(w[s][k][o])
//   with col=nf*16+(lane&15), s=col>>7, o=col&127,
//        k = kc8*64 + kk*32 + (lane>>4)*8 + j.
__global__ __launch_bounds__(512) void fused_pre(
    const int* __restrict__ rows, const float* __restrict__ w,
    uint32_t* __restrict__ maskbuf, int* __restrict__ gcnt,
    unsigned short* __restrict__ b16r) {
  const int t  = threadIdx.x;
  const int bb = blockIdx.x;
  if (bb < NCH) {
    __shared__ int hist[NB];
    for (int b = t; b < NB; b += 512) hist[b] = 0;
    __syncthreads();
    int e0 = bb * CH;
#pragma unroll
    for (int i = 0; i < EPT; ++i) {
      int e = e0 + i * 512 + t;
      if (e < NEDGE) {
        int s = (e >= EDGES) ? 1 : 0;
        int grow = s * N_NODES + rows[e];
        atomicAdd(&hist[grow >> 7], 1);
      }
    }
    __syncthreads();
    for (int b = t; b < NB; b += 512)
      if (hist[b]) atomicAdd(&gcnt[b], hist[b]);
  } else if (bb < NCH + NMB) {
    int wid = (bb - NCH) * 512 + t;
    if (wid < NMASKW) {
      uint32_t base = (uint32_t)wid * 32u;
      uint32_t m = 0u;
#pragma unroll 8
      for (int j = 0; j < 32; ++j)
        m |= (keep_mask(base + j) ? 1u : 0u) << j;
      maskbuf[wid] = m;
    }
  } else {
    int i = (bb - NCH - NMB) * 512 + t;
    if (i < NSUP * DIN * DOUT) {
      int j    = i & 7;
      int lane = (i >> 3) & 63;
      int kk   = (i >> 9) & 1;
      int nf   = (i >> 10) & 15;
      int kc8  = (i >> 14) & 7;
      int col  = nf * 16 + (lane & 15);
      int s    = col >> 7, o = col & 127;
      int k    = kc8 * 64 + kk * 32 + ((lane >> 4) << 3) + j;
      b16r[i] = (unsigned short)bf16rne(w[((size_t)s * DIN + k) * DOUT + o]);
    }
  }
}

// ---- bf16 MFMA GEMM, max-TLP: 16-row blocks, 4 waves sharing rows ----
// Block = rows m0..m0+15; wave w owns col quarter w*64..+63 -> acc[4] frags.
// No LDS, no barriers. All 4 waves issue identical A-loads (L1/L2-served,
// HBM x-traffic stays 1x). B streamed fragment-order from b16r (L2-hot).
// Grid = 3125 blocks = 12.2 blocks/CU -> ~49 waves/CU submitted (VGPR-capped
// lower) vs <=12 in all prior variants: latency hiding via TLP.
__global__ __launch_bounds__(256) void gemm_wide(
    const float* __restrict__ x, const uint32_t* __restrict__ maskbuf,
    const unsigned short* __restrict__ b16r,
    unsigned short* __restrict__ pre16) {
  const int t    = threadIdx.x;
  const int lane = t & 63;
  const int w    = t >> 6;                 // col quarter 0..3
  const int m0   = blockIdx.x * 16;
  const int rowa = m0 + (lane & 15);
  const int rowc = rowa < N_NODES ? rowa : N_NODES - 1;  // clamp; never stored
  const int k8   = (lane >> 4) * 8;
  const float* xrow = x + (size_t)rowc * DIN;
  const int mrow = rowc * 16;

  f32x4 acc[4];
#pragma unroll
  for (int i = 0; i < 4; ++i) acc[i] = (f32x4){0.f, 0.f, 0.f, 0.f};

  float4 pa[2][2][2];            // [slot][kk][half], literal-indexed only
  uint32_t pmw[2][2];

#define LOADA(KC, S)                                                          \
  {                                                                           \
    const float4* a0_ = reinterpret_cast<const float4*>(xrow + (KC) + k8);    \
    pa[S][0][0] = a0_[0];                                                     \
    pa[S][0][1] = a0_[1];                                                     \
    const float4* a1_ =                                                       \
        reinterpret_cast<const float4*>(xrow + (KC) + 32 + k8);               \
    pa[S][1][0] = a1_[0];                                                     \
    pa[S][1][1] = a1_[1];                                                     \
    pmw[S][0] = maskbuf[mrow + ((KC) >> 5)];                                  \
    pmw[S][1] = maskbuf[mrow + ((KC) >> 5) + 1];                              \
  }

  LOADA(0, 0);

#pragma unroll
  for (int kc8 = 0; kc8 < 8; ++kc8) {
    if (kc8 < 7) {
      if ((kc8 & 1) == 0) { LOADA(kc8 * 64 + 64, 1); }
      else                { LOADA(kc8 * 64 + 64, 0); }
    }
    short8 a0, a1;
    if ((kc8 & 1) == 0) {
      a0 = conv8(pa[0][0][0], pa[0][0][1], pmw[0][0] >> k8);
      a1 = conv8(pa[0][1][0], pa[0][1][1], pmw[0][1] >> k8);
    } else {
      a0 = conv8(pa[1][0][0], pa[1][0][1], pmw[1][0] >> k8);
      a1 = conv8(pa[1][1][0], pa[1][1][1], pmw[1][1] >> k8);
    }
    // B stream: fragment-order, lane-contiguous 16B, this wave's col quarter
    const unsigned short* bbase = b16r + (size_t)kc8 * 16384 + lane * 8;
#pragma unroll
    for (int nfl = 0; nfl < 4; ++nfl) {
      int nf = w * 4 + nfl;
      short8 b0 = *reinterpret_cast<const short8*>(bbase + nf * 1024);
      short8 b1 = *reinterpret_cast<const short8*>(bbase + nf * 1024 + 512);
      acc[nfl] = __builtin_amdgcn_mfma_f32_16x16x32_bf16(a0, b0, acc[nfl], 0, 0, 0);
      acc[nfl] = __builtin_amdgcn_mfma_f32_16x16x32_bf16(a1, b1, acc[nfl], 0, 0, 0);
    }
  }
#undef LOADA

  // epilogue: C/D layout col=lane&15, row=(lane>>4)*4+q (m89-verified)
  const int rb = m0 + ((lane >> 4) * 4);
#pragma unroll
  for (int nfl = 0; nfl < 4; ++nfl) {
    int col = (w * 4 + nfl) * 16 + (lane & 15);
    int s = col >> 7, o = col & 127;
#pragma unroll
    for (int q = 0; q < 4; ++q) {
      int row = rb + q;
      if (row < N_NODES)
        pre16[(size_t)(s * N_NODES + row) * DOUT + o] =
            (unsigned short)bf16rne(acc[nfl][q]);
    }
  }
}

// ---- exclusive scan of 782 bucket counts ----
__global__ __launch_bounds__(1024) void scan782(const int* __restrict__ gcnt,
                                                int* __restrict__ bstart,
                                                int* __restrict__ gcursor) {
  __shared__ int sm[1024];
  int t = threadIdx.x;
  int c = (t < NB) ? gcnt[t] : 0;
  sm[t] = c;
  __syncthreads();
  for (int d = 1; d < 1024; d <<= 1) {
    int v = sm[t];
    int a = (t >= d) ? sm[t - d] : 0;
    __syncthreads();
    sm[t] = v + a;
    __syncthreads();
  }
  if (t < NB) {
    int ex = sm[t] - c;
    bstart[t] = ex;
    gcursor[t] = ex;
  }
  if (t == NB - 1) bstart[NB] = sm[t];
}

// ---- LDS-binned scatter: edges -> binned[] grouped by bucket, coalesced flush ----
__global__ __launch_bounds__(512) void bin_scatter(
    const int* __restrict__ rows, const int* __restrict__ cols,
    const float* __restrict__ vals, int* __restrict__ gcursor,
    uint64_t* __restrict__ binned) {
  __shared__ uint32_t hist[NB];
  __shared__ uint32_t hexcl[NB];
  __shared__ uint32_t sbase[NB];
  __shared__ uint32_t scanb[512];
  __shared__ uint64_t ordered[CH];      // 64KB
  __shared__ uint16_t bk16[CH];         // 16KB
  int t = threadIdx.x;
  for (int b = t; b < NB; b += 512) hist[b] = 0;
  __syncthreads();
  int e0 = blockIdx.x * CH;
  uint32_t key[EPT], rank[EPT], bkt[EPT], vbits[EPT];
#pragma unroll
  for (int i = 0; i < EPT; ++i) {
    int e = e0 + i * 512 + t;
    if (e < NEDGE) {
      int s = (e >= EDGES) ? 1 : 0;
      uint32_t grow = (uint32_t)(s * N_NODES + rows[e]);
      uint32_t gcol = (uint32_t)(s * N_NODES + cols[e]);
      vbits[i] = __float_as_uint(vals[e]);
      uint32_t b = grow >> 7;
      bkt[i] = b;
      key[i] = ((grow & 127u) << 17) | gcol;
      rank[i] = atomicAdd(&hist[b], 1u);
    } else {
      bkt[i] = 0xFFFFFFFFu;
    }
  }
  __syncthreads();
  int t2 = t * 2;
  uint32_t a0 = (t2 < NB) ? hist[t2] : 0u;
  uint32_t a1 = (t2 + 1 < NB) ? hist[t2 + 1] : 0u;
  scanb[t] = a0 + a1;
  __syncthreads();
  for (int d = 1; d < 512; d <<= 1) {
    uint32_t v = scanb[t];
    uint32_t a = (t >= d) ? scanb[t - d] : 0u;
    __syncthreads();
    scanb[t] = v + a;
    __syncthreads();
  }
  uint32_t base  = t ? scanb[t - 1] : 0u;
  uint32_t total = scanb[511];
  if (t2 < NB)     hexcl[t2]     = base;
  if (t2 + 1 < NB) hexcl[t2 + 1] = base + a0;
  for (int b = t; b < NB; b += 512)
    if (hist[b]) sbase[b] = (uint32_t)atomicAdd(&gcursor[b], (int)hist[b]);
  __syncthreads();
#pragma unroll
  for (int i = 0; i < EPT; ++i) {
    if (bkt[i] != 0xFFFFFFFFu) {
      uint32_t slot = hexcl[bkt[i]] + rank[i];
      ordered[slot] = ((uint64_t)vbits[i] << 32) | key[i];
      bk16[slot] = (uint16_t)bkt[i];
    }
  }
  __syncthreads();
#pragma unroll
  for (int i = 0; i < EPT; ++i) {
    uint32_t slot = (uint32_t)(i * 512 + t);
    if (slot < total) {
      uint32_t b = bk16[slot];
      uint32_t dst = sbase[b] + (slot - hexcl[b]);
      binned[dst] = ordered[slot];
    }
  }
}

// ---- fused: per-bucket counting sort (LDS) + pull SpMM + ReLU ----
__global__ __launch_bounds__(512) void spmm_sort_pull(
    const int* __restrict__ bstart, const uint64_t* __restrict__ binned,
    const uint32_t* __restrict__ preu, float* __restrict__ out) {
  __shared__ uint64_t ordered[SCAP];    // 32KB
  __shared__ uint32_t hist[128];
  __shared__ uint32_t excl[128];
  const int t = threadIdx.x;
  const int b = blockIdx.x;
  const int beg = bstart[b], end = bstart[b + 1];
  const int cnt = end - beg;
  if (t < 128) hist[t] = 0;
  __syncthreads();
  uint64_t ed[8];
  uint32_t rk[8], rw[8];
#pragma unroll
  for (int i = 0; i < 8; ++i) {
    int slot = i * 512 + t;
    if (slot < cnt) {
      uint64_t e = binned[beg + slot];
      ed[i] = e;
      uint32_t rowin = ((uint32_t)e >> 17) & 127u;
      rw[i] = rowin;
      rk[i] = atomicAdd(&hist[rowin], 1u);
    } else {
      rw[i] = 0xFFFFFFFFu;
    }
  }
  __syncthreads();
  if (t < 128) excl[t] = hist[t];
  __syncthreads();
  for (int d = 1; d < 128; d <<= 1) {
    uint32_t v = (t < 128) ? excl[t] : 0u;
    uint32_t a = (t >= d && t < 128) ? excl[t - d] : 0u;
    __syncthreads();
    if (t < 128) excl[t] = v + a;
    __syncthreads();
  }
  if (t < 128) excl[t] -= hist[t];      // exclusive
  __syncthreads();
#pragma unroll
  for (int i = 0; i < 8; ++i)
    if (rw[i] != 0xFFFFFFFFu)
      ordered[excl[rw[i]] + rk[i]] = ed[i];
  __syncthreads();

  const int lane = t & 63, wave = t >> 6;
  for (int r8 = 0; r8 < 16; ++r8) {
    int r = wave * 16 + r8;
    int grow = b * 128 + r;
    if (grow >= NROWS) break;
    int jbeg = excl[r];
    int jend = jbeg + (int)hist[r];
    float a0 = 0.f, a1 = 0.f;
    int j = jbeg;
    for (; j + 4 <= jend; j += 4) {
      uint64_t e0 = ordered[j],     e1 = ordered[j + 1];
      uint64_t e2 = ordered[j + 2], e3 = ordered[j + 3];
      uint32_t q0 = preu[(size_t)((uint32_t)e0 & 0x1FFFFu) * 64 + lane];
      uint32_t q1 = preu[(size_t)((uint32_t)e1 & 0x1FFFFu) * 64 + lane];
      uint32_t q2 = preu[(size_t)((uint32_t)e2 & 0x1FFFFu) * 64 + lane];
      uint32_t q3 = preu[(size_t)((uint32_t)e3 & 0x1FFFFu) * 64 + lane];
      float v0 = __uint_as_float((uint32_t)(e0 >> 32));
      float v1 = __uint_as_float((uint32_t)(e1 >> 32));
      float v2 = __uint_as_float((uint32_t)(e2 >> 32));
      float v3 = __uint_as_float((uint32_t)(e3 >> 32));
      a0 += v0 * __uint_as_float(q0 << 16);
      a1 += v0 * __uint_as_float(q0 & 0xffff0000u);
      a0 += v1 * __uint_as_float(q1 << 16);
      a1 += v1 * __uint_as_float(q1 & 0xffff0000u);
      a0 += v2 * __uint_as_float(q2 << 16);
      a1 += v2 * __uint_as_float(q2 & 0xffff0000u);
      a0 += v3 * __uint_as_float(q3 << 16);
      a1 += v3 * __uint_as_float(q3 & 0xffff0000u);
    }
    for (; j < jend; ++j) {
      uint64_t e = ordered[j];
      uint32_t q = preu[(size_t)((uint32_t)e & 0x1FFFFu) * 64 + lane];
      float v = __uint_as_float((uint32_t)(e >> 32));
      a0 += v * __uint_as_float(q << 16);
      a1 += v * __uint_as_float(q & 0xffff0000u);
    }
    float2 o = make_float2(fmaxf(a0, 0.f), fmaxf(a1, 0.f));
    *reinterpret_cast<float2*>(out + (size_t)grow * DOUT + 2 * lane) = o;
  }
}

extern "C" void kernel_launch(void* const* d_in, const int* in_sizes, int n_in,
                              void* d_out, int out_size, void* d_ws, size_t ws_size,
                              hipStream_t stream) {
  const float* x    = (const float*)d_in[0];
  const float* w    = (const float*)d_in[1];
  const int*   rows = (const int*)d_in[2];
  const int*   cols = (const int*)d_in[3];
  const float* vals = (const float*)d_in[4];
  float* out = (float*)d_out;

  // ws layout (u32 units); total = 10,467,936 u32 = 41.9MB (< proven 51.2MB)
  uint32_t* base = (uint32_t*)d_ws;
  uint32_t* preu       = base;                              // 6,400,000
  unsigned short* b16r = (unsigned short*)(base + 6400000); // 65,536 u32
  uint32_t* maskbuf    = base + 6400000 + 65536;            // 800,000
  int* gcnt      = (int*)(base + 6400000 + 65536 + 800000); // 800
  int* bstart    = gcnt + 800;                              // 800
  int* gcursor   = bstart + 800;                            // 800
  uint64_t* binned = (uint64_t*)(gcursor + 800);            // 1.6M x 8B
  size_t need = ((size_t)6400000 + 65536 + 800000 + 2400 + 3200000) * 4;
  if (ws_size < need) return;  // loud fail

  hipMemsetAsync(gcnt, 0, NB * sizeof(int), stream);

  fused_pre<<<NCH + NMB + NWC, 512, 0, stream>>>(rows, w, maskbuf, gcnt, b16r);
  scan782<<<1, 1024, 0, stream>>>(gcnt, bstart, gcursor);
  bin_scatter<<<NCH, 512, 0, stream>>>(rows, cols, vals, gcursor, binned);

  gemm_wide<<<N_NODES / 16, 256, 0, stream>>>(x, maskbuf, b16r,
                                              (unsigned short*)preu);

  spmm_sort_pull<<<NB, 512, 0, stream>>>(bstart, binned, preu, out);
}

// Round 18
// 191.268 us; speedup vs baseline: 1.1916x; 1.1916x over previous
//
#include <hip/hip_runtime.h>
#include <stdint.h>

#define N_NODES 50000
#define DIN     512
#define DOUT    128
#define NSUP    2
#define EDGES   800000
#define NEDGE   (NSUP * EDGES)        // 1,600,000
#define NROWS   (NSUP * N_NODES)      // 100,000
#define NB      782                   // ceil(NROWS/128)
#define CH      8192                  // edges per chunk
#define NCH     ((NEDGE + CH - 1) / CH)   // 196
#define EPT     16                    // CH / 512 threads
#define SCAP    4096                  // per-bucket LDS edge capacity (max ~2300)
#define NMASKW  ((N_NODES * DIN) / 32)    // 800,000 mask words
#define NMB     1563                  // mask blocks: 1563*512 = 800,256 threads
#define NWC     256                   // wcvt blocks: 256*512 = 131,072 elems

typedef __attribute__((ext_vector_type(8))) short short8;
typedef __attribute__((ext_vector_type(4))) float f32x4;

// ---- JAX threefry2x32, key(42) -> (0,42); partitionable, bits = o0^o1 (verified R1) ----
__device__ __forceinline__ uint32_t rotl32(uint32_t v, uint32_t d) {
  return (v << d) | (v >> (32u - d));
}

__device__ __forceinline__ void threefry2x32(uint32_t x0, uint32_t x1,
                                             uint32_t& o0, uint32_t& o1) {
  const uint32_t ks0 = 0u;
  const uint32_t ks1 = 42u;
  const uint32_t ks2 = 0u ^ 42u ^ 0x1BD11BDAu;
  x0 += ks0; x1 += ks1;
#define TF_R(r) { x0 += x1; x1 = rotl32(x1, (r)); x1 ^= x0; }
  TF_R(13) TF_R(15) TF_R(26) TF_R(6)
  x0 += ks1; x1 += ks2 + 1u;
  TF_R(17) TF_R(29) TF_R(16) TF_R(24)
  x0 += ks2; x1 += ks0 + 2u;
  TF_R(13) TF_R(15) TF_R(26) TF_R(6)
  x0 += ks0; x1 += ks1 + 3u;
  TF_R(17) TF_R(29) TF_R(16) TF_R(24)
  x0 += ks1; x1 += ks2 + 4u;
  TF_R(13) TF_R(15) TF_R(26) TF_R(6)
  x0 += ks2; x1 += ks0 + 5u;
#undef TF_R
  o0 = x0; o1 = x1;
}

__device__ __forceinline__ bool keep_mask(uint32_t idx) {
  uint32_t o0, o1;
  threefry2x32(0u, idx, o0, o1);
  // u = float(((o0^o1)>>9)|0x3F800000) - 1 < 0.5  <=>  top bit of (o0^o1) is 0
  return ((o0 ^ o1) >> 31) == 0u;
}

__device__ __forceinline__ uint32_t pack_bf16x2(float a, float b) {
  uint32_t ua = __float_as_uint(a), ub = __float_as_uint(b);
  ua += 0x7fffu + ((ua >> 16) & 1u);
  ub += 0x7fffu + ((ub >> 16) & 1u);
  return (ua >> 16) | (ub & 0xffff0000u);
}

__device__ __forceinline__ uint32_t bf16rne(float f) {
  uint32_t u = __float_as_uint(f);
  u += 0x7fffu + ((u >> 16) & 1u);
  return u >> 16;
}

// ---- heterogeneous fused pre-pass ----
// blocks [0, NCH):            edge bucket histogram (memory-bound)
// blocks [NCH, NCH+NMB):      dropout mask, 1 word/thread, unroll-8 ILP (VALU-bound)
// blocks [NCH+NMB, +NWC):     W fp32 -> B16t [256 cols][512 k] bf16 transpose+cvt
__global__ __launch_bounds__(512) void fused_pre(
    const int* __restrict__ rows, const float* __restrict__ w,
    uint32_t* __restrict__ maskbuf, int* __restrict__ gcnt,
    unsigned short* __restrict__ b16t) {
  const int t  = threadIdx.x;
  const int bb = blockIdx.x;
  if (bb < NCH) {
    __shared__ int hist[NB];
    for (int b = t; b < NB; b += 512) hist[b] = 0;
    __syncthreads();
    int e0 = bb * CH;
#pragma unroll
    for (int i = 0; i < EPT; ++i) {
      int e = e0 + i * 512 + t;
      if (e < NEDGE) {
        int s = (e >= EDGES) ? 1 : 0;
        int grow = s * N_NODES + rows[e];
        atomicAdd(&hist[grow >> 7], 1);
      }
    }
    __syncthreads();
    for (int b = t; b < NB; b += 512)
      if (hist[b]) atomicAdd(&gcnt[b], hist[b]);
  } else if (bb < NCH + NMB) {
    int wid = (bb - NCH) * 512 + t;
    if (wid < NMASKW) {
      uint32_t base = (uint32_t)wid * 32u;
      uint32_t m = 0u;
#pragma unroll 8
      for (int j = 0; j < 32; ++j)
        m |= (keep_mask(base + j) ? 1u : 0u) << j;
      maskbuf[wid] = m;
    }
  } else {
    int i = (bb - NCH - NMB) * 512 + t;
    if (i < NSUP * DIN * DOUT) {
      int s   = i >> 16;
      int rem = i & 65535;
      int k   = rem >> 7;
      int o   = rem & 127;
      b16t[(size_t)(s * DOUT + o) * DIN + k] = (unsigned short)bf16rne(w[i]);
    }
  }
}

// ---- bf16 MFMA GEMM, software-pipelined (register prefetch -> LDS commit) ----
// BM=64, BN=256, BK=64. 512 threads = 8 waves; wave wc owns rows 0..63 x cols
// wc*32..+31 -> acc[4 mf][2 nf]. XOR swizzle on As/Bs (u16 idx ^= (row&7)<<3).
__global__ __launch_bounds__(512) void gemm_mfma3(
    const float* __restrict__ x, const uint32_t* __restrict__ maskbuf,
    const unsigned short* __restrict__ b16t,
    unsigned short* __restrict__ pre16) {
  __shared__ unsigned short As[64 * 64];    // 8KB
  __shared__ unsigned short Bs[256 * 64];   // 32KB
  const int t    = threadIdx.x;
  const int lane = t & 63;
  const int wc   = t >> 6;                  // 0..7
  const int m0   = blockIdx.x * 64;

  f32x4 acc[4][2];
#pragma unroll
  for (int i = 0; i < 4; ++i)
#pragma unroll
    for (int j = 0; j < 2; ++j) acc[i][j] = (f32x4){0.f, 0.f, 0.f, 0.f};

  // A staging geometry: 64 rows x 64 k = 8 fp32/thread
  const int arow  = t >> 3;                 // 0..63
  const int ak8   = (t & 7) * 8;
  const int agrow = m0 + arow;
  const bool avalid = agrow < N_NODES;
  const uint32_t abase = (uint32_t)agrow * DIN + (uint32_t)ak8;
  const int aswz  = (arow * 64 + ak8) ^ ((arow & 7) << 3);

  // prefetch registers
  float4 pa0, pa1;
  uint32_t pm = 0u;
  short8 pb[4];

#define LOADCH(KC)                                                         \
  {                                                                        \
    if (avalid) {                                                          \
      const float4* s_ = reinterpret_cast<const float4*>(x + abase + (KC)); \
      pa0 = s_[0];                                                         \
      pa1 = s_[1];                                                         \
      uint32_t b8_ = abase + (uint32_t)(KC);                               \
      pm = maskbuf[b8_ >> 5] >> (b8_ & 31u);                               \
    }                                                                      \
    _Pragma("unroll")                                                      \
    for (int i_ = 0; i_ < 4; ++i_) {                                       \
      int slot_ = i_ * 512 + t;                                            \
      int col_  = slot_ >> 3;                                              \
      int k8_   = (slot_ & 7) * 8;                                         \
      pb[i_] = *reinterpret_cast<const short8*>(                           \
          b16t + (size_t)col_ * DIN + (KC) + k8_);                         \
    }                                                                      \
  }

  LOADCH(0);

  for (int kc8 = 0; kc8 < 8; ++kc8) {
    const int kc = kc8 * 64;
    __syncthreads();   // LDS free (consumed by previous iteration's frag reads)
    // commit prefetched chunk to LDS (mask-apply + bf16 pack on A)
    {
      union { uint32_t u[4]; short8 s; } pk;
      if (avalid) {
        float f[8] = {pa0.x, pa0.y, pa0.z, pa0.w, pa1.x, pa1.y, pa1.z, pa1.w};
#pragma unroll
        for (int q = 0; q < 8; ++q)
          f[q] = ((pm >> q) & 1u) ? f[q] * 2.0f : 0.0f;
#pragma unroll
        for (int q = 0; q < 4; ++q) pk.u[q] = pack_bf16x2(f[2 * q], f[2 * q + 1]);
      } else {
#pragma unroll
        for (int q = 0; q < 4; ++q) pk.u[q] = 0u;
      }
      *reinterpret_cast<short8*>(&As[aswz]) = pk.s;
    }
#pragma unroll
    for (int i = 0; i < 4; ++i) {
      int slot = i * 512 + t;
      int col  = slot >> 3;
      int k8   = (slot & 7) * 8;
      *reinterpret_cast<short8*>(&Bs[(col * 64 + k8) ^ ((col & 7) << 3)]) = pb[i];
    }
    // issue next chunk's global loads NOW -> latency hides under MFMA phase
    if (kc8 < 7) LOADCH(kc + 64);
    __syncthreads();   // LDS ready

    short8 af[4][2], bf[2][2];
#pragma unroll
    for (int mf = 0; mf < 4; ++mf)
#pragma unroll
      for (int kk = 0; kk < 2; ++kk) {
        int row = mf * 16 + (lane & 15);
        int idx = (row * 64 + kk * 32 + (lane >> 4) * 8) ^ ((row & 7) << 3);
        af[mf][kk] = *reinterpret_cast<const short8*>(&As[idx]);
      }
#pragma unroll
    for (int kk = 0; kk < 2; ++kk)
#pragma unroll
      for (int nf = 0; nf < 2; ++nf) {
        int col = wc * 32 + nf * 16 + (lane & 15);
        int idx = (col * 64 + kk * 32 + (lane >> 4) * 8) ^ ((col & 7) << 3);
        bf[kk][nf] = *reinterpret_cast<const short8*>(&Bs[idx]);
      }
#pragma unroll
    for (int mf = 0; mf < 4; ++mf)
#pragma unroll
      for (int nf = 0; nf < 2; ++nf)
#pragma unroll
        for (int kk = 0; kk < 2; ++kk)
          acc[mf][nf] = __builtin_amdgcn_mfma_f32_16x16x32_bf16(
              af[mf][kk], bf[kk][nf], acc[mf][nf], 0, 0, 0);
  }
#undef LOADCH

  // epilogue: C/D layout col=lane&15, row=(lane>>4)*4+q (m89-verified)
#pragma unroll
  for (int mf = 0; mf < 4; ++mf) {
    int rbase = m0 + mf * 16 + ((lane >> 4) * 4);
#pragma unroll
    for (int nf = 0; nf < 2; ++nf) {
      int col = wc * 32 + nf * 16 + (lane & 15);
      int s = col >> 7, o = col & 127;
#pragma unroll
      for (int q = 0; q < 4; ++q) {
        int row = rbase + q;
        if (row < N_NODES)
          pre16[(size_t)(s * N_NODES + row) * DOUT + o] =
              (unsigned short)bf16rne(acc[mf][nf][q]);
      }
    }
  }
}

// ---- exclusive scan of 782 bucket counts ----
__global__ __launch_bounds__(1024) void scan782(const int* __restrict__ gcnt,
                                                int* __restrict__ bstart,
                                                int* __restrict__ gcursor) {
  __shared__ int sm[1024];
  int t = threadIdx.x;
  int c = (t < NB) ? gcnt[t] : 0;
  sm[t] = c;
  __syncthreads();
  for (int d = 1; d < 1024; d <<= 1) {
    int v = sm[t];
    int a = (t >= d) ? sm[t - d] : 0;
    __syncthreads();
    sm[t] = v + a;
    __syncthreads();
  }
  if (t < NB) {
    int ex = sm[t] - c;
    bstart[t] = ex;
    gcursor[t] = ex;
  }
  if (t == NB - 1) bstart[NB] = sm[t];
}

// ---- LDS-binned scatter: edges -> binned[] grouped by bucket, coalesced flush ----
__global__ __launch_bounds__(512) void bin_scatter(
    const int* __restrict__ rows, const int* __restrict__ cols,
    const float* __restrict__ vals, int* __restrict__ gcursor,
    uint64_t* __restrict__ binned) {
  __shared__ uint32_t hist[NB];
  __shared__ uint32_t hexcl[NB];
  __shared__ uint32_t sbase[NB];
  __shared__ uint32_t scanb[512];
  __shared__ uint64_t ordered[CH];      // 64KB
  __shared__ uint16_t bk16[CH];         // 16KB
  int t = threadIdx.x;
  for (int b = t; b < NB; b += 512) hist[b] = 0;
  __syncthreads();
  int e0 = blockIdx.x * CH;
  uint32_t key[EPT], rank[EPT], bkt[EPT], vbits[EPT];
#pragma unroll
  for (int i = 0; i < EPT; ++i) {
    int e = e0 + i * 512 + t;
    if (e < NEDGE) {
      int s = (e >= EDGES) ? 1 : 0;
      uint32_t grow = (uint32_t)(s * N_NODES + rows[e]);
      uint32_t gcol = (uint32_t)(s * N_NODES + cols[e]);
      vbits[i] = __float_as_uint(vals[e]);
      uint32_t b = grow >> 7;
      bkt[i] = b;
      key[i] = ((grow & 127u) << 17) | gcol;
      rank[i] = atomicAdd(&hist[b], 1u);
    } else {
      bkt[i] = 0xFFFFFFFFu;
    }
  }
  __syncthreads();
  int t2 = t * 2;
  uint32_t a0 = (t2 < NB) ? hist[t2] : 0u;
  uint32_t a1 = (t2 + 1 < NB) ? hist[t2 + 1] : 0u;
  scanb[t] = a0 + a1;
  __syncthreads();
  for (int d = 1; d < 512; d <<= 1) {
    uint32_t v = scanb[t];
    uint32_t a = (t >= d) ? scanb[t - d] : 0u;
    __syncthreads();
    scanb[t] = v + a;
    __syncthreads();
  }
  uint32_t base  = t ? scanb[t - 1] : 0u;
  uint32_t total = scanb[511];
  if (t2 < NB)     hexcl[t2]     = base;
  if (t2 + 1 < NB) hexcl[t2 + 1] = base + a0;
  for (int b = t; b < NB; b += 512)
    if (hist[b]) sbase[b] = (uint32_t)atomicAdd(&gcursor[b], (int)hist[b]);
  __syncthreads();
#pragma unroll
  for (int i = 0; i < EPT; ++i) {
    if (bkt[i] != 0xFFFFFFFFu) {
      uint32_t slot = hexcl[bkt[i]] + rank[i];
      ordered[slot] = ((uint64_t)vbits[i] << 32) | key[i];
      bk16[slot] = (uint16_t)bkt[i];
    }
  }
  __syncthreads();
#pragma unroll
  for (int i = 0; i < EPT; ++i) {
    uint32_t slot = (uint32_t)(i * 512 + t);
    if (slot < total) {
      uint32_t b = bk16[slot];
      uint32_t dst = sbase[b] + (slot - hexcl[b]);
      binned[dst] = ordered[slot];
    }
  }
}

// ---- fused: per-bucket counting sort (LDS) + pull SpMM + ReLU ----
__global__ __launch_bounds__(512) void spmm_sort_pull(
    const int* __restrict__ bstart, const uint64_t* __restrict__ binned,
    const uint32_t* __restrict__ preu, float* __restrict__ out) {
  __shared__ uint64_t ordered[SCAP];    // 32KB
  __shared__ uint32_t hist[128];
  __shared__ uint32_t excl[128];
  const int t = threadIdx.x;
  const int b = blockIdx.x;
  const int beg = bstart[b], end = bstart[b + 1];
  const int cnt = end - beg;
  if (t < 128) hist[t] = 0;
  __syncthreads();
  uint64_t ed[8];
  uint32_t rk[8], rw[8];
#pragma unroll
  for (int i = 0; i < 8; ++i) {
    int slot = i * 512 + t;
    if (slot < cnt) {
      uint64_t e = binned[beg + slot];
      ed[i] = e;
      uint32_t rowin = ((uint32_t)e >> 17) & 127u;
      rw[i] = rowin;
      rk[i] = atomicAdd(&hist[rowin], 1u);
    } else {
      rw[i] = 0xFFFFFFFFu;
    }
  }
  __syncthreads();
  if (t < 128) excl[t] = hist[t];
  __syncthreads();
  for (int d = 1; d < 128; d <<= 1) {
    uint32_t v = (t < 128) ? excl[t] : 0u;
    uint32_t a = (t >= d && t < 128) ? excl[t - d] : 0u;
    __syncthreads();
    if (t < 128) excl[t] = v + a;
    __syncthreads();
  }
  if (t < 128) excl[t] -= hist[t];      // exclusive
  __syncthreads();
#pragma unroll
  for (int i = 0; i < 8; ++i)
    if (rw[i] != 0xFFFFFFFFu)
      ordered[excl[rw[i]] + rk[i]] = ed[i];
  __syncthreads();

  // pull phase: wave w handles 16 rows
  const int lane = t & 63, wave = t >> 6;
  for (int r8 = 0; r8 < 16; ++r8) {
    int r = wave * 16 + r8;
    int grow = b * 128 + r;
    if (grow >= NROWS) break;
    int jbeg = excl[r];
    int jend = jbeg + (int)hist[r];
    float a0 = 0.f, a1 = 0.f;
    int j = jbeg;
    for (; j + 4 <= jend; j += 4) {
      uint64_t e0 = ordered[j],     e1 = ordered[j + 1];
      uint64_t e2 = ordered[j + 2], e3 = ordered[j + 3];
      uint32_t q0 = preu[(size_t)((uint32_t)e0 & 0x1FFFFu) * 64 + lane];
      uint32_t q1 = preu[(size_t)((uint32_t)e1 & 0x1FFFFu) * 64 + lane];
      uint32_t q2 = preu[(size_t)((uint32_t)e2 & 0x1FFFFu) * 64 + lane];
      uint32_t q3 = preu[(size_t)((uint32_t)e3 & 0x1FFFFu) * 64 + lane];
      float v0 = __uint_as_float((uint32_t)(e0 >> 32));
      float v1 = __uint_as_float((uint32_t)(e1 >> 32));
      float v2 = __uint_as_float((uint32_t)(e2 >> 32));
      float v3 = __uint_as_float((uint32_t)(e3 >> 32));
      a0 += v0 * __uint_as_float(q0 << 16);
      a1 += v0 * __uint_as_float(q0 & 0xffff0000u);
      a0 += v1 * __uint_as_float(q1 << 16);
      a1 += v1 * __uint_as_float(q1 & 0xffff0000u);
      a0 += v2 * __uint_as_float(q2 << 16);
      a1 += v2 * __uint_as_float(q2 & 0xffff0000u);
      a0 += v3 * __uint_as_float(q3 << 16);
      a1 += v3 * __uint_as_float(q3 & 0xffff0000u);
    }
    for (; j < jend; ++j) {
      uint64_t e = ordered[j];
      uint32_t q = preu[(size_t)((uint32_t)e & 0x1FFFFu) * 64 + lane];
      float v = __uint_as_float((uint32_t)(e >> 32));
      a0 += v * __uint_as_float(q << 16);
      a1 += v * __uint_as_float(q & 0xffff0000u);
    }
    float2 o = make_float2(fmaxf(a0, 0.f), fmaxf(a1, 0.f));
    *reinterpret_cast<float2*>(out + (size_t)grow * DOUT + 2 * lane) = o;
  }
}

extern "C" void kernel_launch(void* const* d_in, const int* in_sizes, int n_in,
                              void* d_out, int out_size, void* d_ws, size_t ws_size,
                              hipStream_t stream) {
  const float* x    = (const float*)d_in[0];
  const float* w    = (const float*)d_in[1];
  const int*   rows = (const int*)d_in[2];
  const int*   cols = (const int*)d_in[3];
  const float* vals = (const float*)d_in[4];
  float* out = (float*)d_out;

  // ws layout (u32 units); total = 10,467,936 u32 = 41.9MB (< proven 51.2MB)
  uint32_t* base = (uint32_t*)d_ws;
  uint32_t* preu       = base;                              // 6,400,000
  unsigned short* b16t = (unsigned short*)(base + 6400000); // 65,536 u32
  uint32_t* maskbuf    = base + 6400000 + 65536;            // 800,000
  int* gcnt      = (int*)(base + 6400000 + 65536 + 800000); // 800
  int* bstart    = gcnt + 800;                              // 800
  int* gcursor   = bstart + 800;                            // 800
  uint64_t* binned = (uint64_t*)(gcursor + 800);            // 1.6M x 8B
  size_t need = ((size_t)6400000 + 65536 + 800000 + 2400 + 3200000) * 4;
  if (ws_size < need) return;  // loud fail

  hipMemsetAsync(gcnt, 0, NB * sizeof(int), stream);

  fused_pre<<<NCH + NMB + NWC, 512, 0, stream>>>(rows, w, maskbuf, gcnt, b16t);
  scan782<<<1, 1024, 0, stream>>>(gcnt, bstart, gcursor);
  bin_scatter<<<NCH, 512, 0, stream>>>(rows, cols, vals, gcursor, binned);

  gemm_mfma3<<<(N_NODES + 63) / 64, 512, 0, stream>>>(x, maskbuf, b16t,
                                                      (unsigned short*)preu);

  spmm_sort_pull<<<NB, 512, 0, stream>>>(bstart, binned, preu, out);
}